// Round 2
// baseline (288.040 us; speedup 1.0000x reference)
//
#include <hip/hip_runtime.h>

#define BB 64
#define DD 256
#define HH 512
#define RR 32
#define CLIPV 50.0f

// Output layout (flat fp32): v_new | new_h | dU_new | new_trace_e | new_trace_E
#define OUT_V   0
#define OUT_H   (BB * HH)                       // 32768
#define OUT_DU  (2 * BB * HH)                   // 65536
#define OUT_TE  (2 * BB * HH + BB * HH * HH)    // 16842752
#define OUT_TEE (3 * BB * HH + BB * HH * HH)    // 16875520

__device__ __forceinline__ float sigmoidf_(float x) {
    return 1.0f / (1.0f + expf(-x));
}

// One wave (64 lanes) per (b, i), i in [0, H+R).
__global__ __launch_bounds__(256) void k_small(
    const float* __restrict__ x, const float* __restrict__ h, const float* __restrict__ v,
    const float* __restrict__ dU, const float* __restrict__ trace_e,
    const float* __restrict__ x2h_w, const float* __restrict__ x2h_b,
    const float* __restrict__ h2h_w, const float* __restrict__ h2h_b,
    const float* __restrict__ alpha,
    const float* __restrict__ tau_v, const float* __restrict__ tau_e,
    float* __restrict__ out, float* __restrict__ mod_ws)
{
    const int wave = blockIdx.x * 4 + (threadIdx.x >> 6);
    const int lane = threadIdx.x & 63;
    const int b = wave / (HH + RR);
    const int i = wave - b * (HH + RR);

    // Wx partial: D=256 = 64 lanes x 4
    float4 xv = *reinterpret_cast<const float4*>(x + b * DD + lane * 4);
    float4 wv = *reinterpret_cast<const float4*>(x2h_w + i * DD + lane * 4);
    float s  = xv.x * wv.x + xv.y * wv.y + xv.z * wv.z + xv.w * wv.w;
    float pl = 0.0f;

    if (i < HH) {
        const float* dUrow = dU + (b * HH + i) * HH;
        const float* arow  = alpha + i * HH;
        #pragma unroll
        for (int p = 0; p < 2; ++p) {
            const int j0 = p * 256 + lane * 4;
            float4 hv  = *reinterpret_cast<const float4*>(h + b * HH + j0);
            float4 whv = *reinterpret_cast<const float4*>(h2h_w + i * HH + j0);
            s += hv.x * whv.x + hv.y * whv.y + hv.z * whv.z + hv.w * whv.w;
            float4 duv = *reinterpret_cast<const float4*>(dUrow + j0);
            float4 av  = *reinterpret_cast<const float4*>(arow + j0);
            pl += fmaxf(av.x, 0.f) * duv.x * hv.x
                + fmaxf(av.y, 0.f) * duv.y * hv.y
                + fmaxf(av.z, 0.f) * duv.z * hv.z
                + fmaxf(av.w, 0.f) * duv.w * hv.w;
        }
    } else {
        #pragma unroll
        for (int p = 0; p < 2; ++p) {
            const int j0 = p * 256 + lane * 4;
            float4 hv  = *reinterpret_cast<const float4*>(h + b * HH + j0);
            float4 whv = *reinterpret_cast<const float4*>(h2h_w + i * HH + j0);
            s += hv.x * whv.x + hv.y * whv.y + hv.z * whv.z + hv.w * whv.w;
        }
    }

    #pragma unroll
    for (int off = 32; off > 0; off >>= 1) {
        s  += __shfl_xor(s, off, 64);
        pl += __shfl_xor(pl, off, 64);
    }

    if (lane == 0) {
        s += x2h_b[i] + h2h_b[i];
        if (i < HH) {
            const int bi = b * HH + i;
            const float dv = s + pl;
            const float sv = sigmoidf_(tau_v[i]);
            const float vn = (1.f - sv) * v[bi] + sv * dv;
            out[OUT_V + bi] = vn;
            out[OUT_H + bi] = fmaxf(vn, 0.f);
            const float se = sigmoidf_(tau_e[i]);
            out[OUT_TE + bi] = (1.f - se) * trace_e[bi] + se * h[bi];
        } else {
            atomicAdd(mod_ws + b, fmaxf(s, 0.f));
        }
    }
}

// Elementwise over B*H*H, float4 grid-stride.
__global__ __launch_bounds__(256) void k_big(
    const float* __restrict__ dU, const float* __restrict__ trace_E,
    const float* __restrict__ h, const float* __restrict__ trace_e,
    const float* __restrict__ alpha, const float* __restrict__ h2h_w,
    const float* __restrict__ tau_U, const float* __restrict__ tau_E,
    const float* __restrict__ mod_ws, float* __restrict__ out)
{
    const float sU = sigmoidf_(tau_U[0]);
    const float sE = sigmoidf_(tau_E[0]);
    const float omU = 1.f - sU, omE = 1.f - sE;
    const float* __restrict__ new_h  = out + OUT_H;
    const float* __restrict__ new_te = out + OUT_TE;
    float* __restrict__ out_dU = out + OUT_DU;
    float* __restrict__ out_tE = out + OUT_TEE;

    const int total = (BB * HH * HH) / 4;  // 4,194,304 float4s
    for (int idx = blockIdx.x * blockDim.x + threadIdx.x; idx < total;
         idx += gridDim.x * blockDim.x) {
        const int flat = idx << 2;            // element index = b*H*H + i*H + j
        const int b   = flat >> 18;
        const int rem = flat & ((1 << 18) - 1);
        const int i   = rem >> 9;
        const int j   = rem & (HH - 1);

        float4 tE = *reinterpret_cast<const float4*>(trace_E + flat);
        float4 du = *reinterpret_cast<const float4*>(dU + flat);
        float4 al = *reinterpret_cast<const float4*>(alpha + rem);   // alpha[0,i,j]
        float4 W  = *reinterpret_cast<const float4*>(h2h_w + rem);   // W_hh[i,j]
        float4 hv = *reinterpret_cast<const float4*>(h + b * HH + j);
        float4 te = *reinterpret_cast<const float4*>(trace_e + b * HH + j);
        const float nh   = new_h[b * HH + i];
        const float nte  = new_te[b * HH + i];
        const float smod = sU * mod_ws[b];

        float4 rE, rU;
        #define COMP(c)                                                  \
        {                                                                \
            const float outer = nh * te.c - nte * hv.c;                  \
            const float nE    = omE * tE.c + sE * outer;                 \
            float dnew        = omU * du.c + smod * nE;                  \
            const float ar    = fmaxf(al.c, 0.f);                        \
            const float inv   = 1.0f / (ar + 1e-8f);                     \
            const float up    = fmaxf(CLIPV - W.c, 0.f) * inv;           \
            const float lo    = -fmaxf(CLIPV + W.c, 0.f) * inv;          \
            rE.c = nE;                                                   \
            rU.c = fmaxf(fminf(dnew, up), lo);                           \
        }
        COMP(x) COMP(y) COMP(z) COMP(w)
        #undef COMP

        *reinterpret_cast<float4*>(out_tE + flat) = rE;
        *reinterpret_cast<float4*>(out_dU + flat) = rU;
    }
}

extern "C" void kernel_launch(void* const* d_in, const int* in_sizes, int n_in,
                              void* d_out, int out_size, void* d_ws, size_t ws_size,
                              hipStream_t stream) {
    const float* x       = (const float*)d_in[0];
    const float* h       = (const float*)d_in[1];
    const float* v       = (const float*)d_in[2];
    const float* dU      = (const float*)d_in[3];
    const float* trace_e = (const float*)d_in[4];
    const float* trace_E = (const float*)d_in[5];
    const float* x2h_w   = (const float*)d_in[6];
    const float* x2h_b   = (const float*)d_in[7];
    const float* h2h_w   = (const float*)d_in[8];
    const float* h2h_b   = (const float*)d_in[9];
    const float* alpha   = (const float*)d_in[10];
    const float* tau_v   = (const float*)d_in[11];
    const float* tau_e   = (const float*)d_in[12];
    const float* tau_U   = (const float*)d_in[13];
    const float* tau_E   = (const float*)d_in[14];
    float* out    = (float*)d_out;
    float* mod_ws = (float*)d_ws;

    hipMemsetAsync(d_ws, 0, BB * sizeof(float), stream);

    const int waves = BB * (HH + RR);          // 34816
    k_small<<<waves / 4, 256, 0, stream>>>(x, h, v, dU, trace_e, x2h_w, x2h_b,
                                           h2h_w, h2h_b, alpha, tau_v, tau_e,
                                           out, mod_ws);
    k_big<<<2048, 256, 0, stream>>>(dU, trace_E, h, trace_e, alpha, h2h_w,
                                    tau_U, tau_E, mod_ws, out);
}

// Round 3
// 281.603 us; speedup vs baseline: 1.0229x; 1.0229x over previous
//
#include <hip/hip_runtime.h>

#define BB 64
#define DD 256
#define HH 512
#define RR 32
#define CLIPV 50.0f

// Output layout (flat fp32): v_new | new_h | dU_new | new_trace_e | new_trace_E
#define OUT_V   0
#define OUT_H   (BB * HH)                       // 32768
#define OUT_DU  (2 * BB * HH)                   // 65536
#define OUT_TE  (2 * BB * HH + BB * HH * HH)    // 16842752
#define OUT_TEE (3 * BB * HH + BB * HH * HH)    // 16875520

__device__ __forceinline__ float sigmoidf_(float x) {
    return 1.0f / (1.0f + expf(-x));
}

// mod[b] = sum_r relu(Wx[b,H+r] + Wh[b,H+r]).  One wave per (b,r): 2048 waves.
// Touches only the R-rows of the weights — no dU traffic.
__global__ __launch_bounds__(256) void k_mod(
    const float* __restrict__ x, const float* __restrict__ h,
    const float* __restrict__ x2h_w, const float* __restrict__ x2h_b,
    const float* __restrict__ h2h_w, const float* __restrict__ h2h_b,
    float* __restrict__ mod_ws)
{
    const int wave = blockIdx.x * 4 + (threadIdx.x >> 6);
    const int lane = threadIdx.x & 63;
    const int b = wave >> 5;          // /32
    const int r = wave & (RR - 1);
    const int i = HH + r;

    float4 xv = *reinterpret_cast<const float4*>(x + b * DD + lane * 4);
    float4 wv = *reinterpret_cast<const float4*>(x2h_w + i * DD + lane * 4);
    float s = xv.x * wv.x + xv.y * wv.y + xv.z * wv.z + xv.w * wv.w;

    #pragma unroll
    for (int p = 0; p < 2; ++p) {
        const int j0 = p * 256 + lane * 4;
        float4 hv  = *reinterpret_cast<const float4*>(h + b * HH + j0);
        float4 whv = *reinterpret_cast<const float4*>(h2h_w + i * HH + j0);
        s += hv.x * whv.x + hv.y * whv.y + hv.z * whv.z + hv.w * whv.w;
    }

    #pragma unroll
    for (int off = 32; off > 0; off >>= 1)
        s += __shfl_xor(s, off, 64);

    if (lane == 0) {
        s += x2h_b[i] + h2h_b[i];
        atomicAdd(mod_ws + b, fmaxf(s, 0.f));
    }
}

// Fused: one wave per (b,i) row, i < H.  32768 waves = 8192 blocks.
// Loads {h, h2h_w, dU, alpha, trace_e} row slices into registers ONCE,
// uses them for the Wh+plastic reduction AND the elementwise pass.
__global__ __launch_bounds__(256) void k_fused(
    const float* __restrict__ x, const float* __restrict__ h, const float* __restrict__ v,
    const float* __restrict__ dU, const float* __restrict__ trace_e,
    const float* __restrict__ trace_E,
    const float* __restrict__ x2h_w, const float* __restrict__ x2h_b,
    const float* __restrict__ h2h_w, const float* __restrict__ h2h_b,
    const float* __restrict__ alpha,
    const float* __restrict__ tau_v, const float* __restrict__ tau_e,
    const float* __restrict__ tau_U, const float* __restrict__ tau_E,
    const float* __restrict__ mod_ws, float* __restrict__ out)
{
    const int wave = blockIdx.x * 4 + (threadIdx.x >> 6);
    const int lane = threadIdx.x & 63;
    const int b = wave >> 9;          // /512
    const int i = wave & (HH - 1);
    const int bi = b * HH + i;

    // ---- reduction phase: Wx + Wh + plastic ----
    float4 xv = *reinterpret_cast<const float4*>(x + b * DD + lane * 4);
    float4 wv = *reinterpret_cast<const float4*>(x2h_w + i * DD + lane * 4);
    float s  = xv.x * wv.x + xv.y * wv.y + xv.z * wv.z + xv.w * wv.w;
    float pl = 0.0f;

    float4 hv[2], wh[2], du[2], av[2], te[2];
    #pragma unroll
    for (int p = 0; p < 2; ++p) {
        const int j0 = p * 256 + lane * 4;
        hv[p] = *reinterpret_cast<const float4*>(h + b * HH + j0);
        wh[p] = *reinterpret_cast<const float4*>(h2h_w + i * HH + j0);
        du[p] = *reinterpret_cast<const float4*>(dU + (size_t)bi * HH + j0);
        av[p] = *reinterpret_cast<const float4*>(alpha + i * HH + j0);
        te[p] = *reinterpret_cast<const float4*>(trace_e + b * HH + j0);
        s += hv[p].x * wh[p].x + hv[p].y * wh[p].y
           + hv[p].z * wh[p].z + hv[p].w * wh[p].w;
        pl += fmaxf(av[p].x, 0.f) * du[p].x * hv[p].x
            + fmaxf(av[p].y, 0.f) * du[p].y * hv[p].y
            + fmaxf(av[p].z, 0.f) * du[p].z * hv[p].z
            + fmaxf(av[p].w, 0.f) * du[p].w * hv[p].w;
    }

    #pragma unroll
    for (int off = 32; off > 0; off >>= 1) {
        s  += __shfl_xor(s, off, 64);
        pl += __shfl_xor(pl, off, 64);
    }

    // ---- row-local scalar state (all lanes compute; same-addr loads broadcast) ----
    s += x2h_b[i] + h2h_b[i];
    const float dv = s + pl;
    const float sv = sigmoidf_(tau_v[i]);
    const float vn = (1.f - sv) * v[bi] + sv * dv;
    const float nh = fmaxf(vn, 0.f);
    const float se = sigmoidf_(tau_e[i]);
    const float nte = (1.f - se) * trace_e[bi] + se * h[bi];

    if (lane == 0) {
        out[OUT_V  + bi] = vn;
        out[OUT_H  + bi] = nh;
        out[OUT_TE + bi] = nte;
    }

    // ---- elementwise phase over the same row ----
    const float sU  = sigmoidf_(tau_U[0]);
    const float sE  = sigmoidf_(tau_E[0]);
    const float omU = 1.f - sU, omE = 1.f - sE;
    const float smod = sU * mod_ws[b];

    float* __restrict__ out_dU = out + OUT_DU;
    float* __restrict__ out_tE = out + OUT_TEE;

    #pragma unroll
    for (int p = 0; p < 2; ++p) {
        const int j0 = p * 256 + lane * 4;
        const size_t flat = (size_t)bi * HH + j0;
        float4 tE = *reinterpret_cast<const float4*>(trace_E + flat);

        float4 rE, rU;
        #define COMP(c)                                                  \
        {                                                                \
            const float outer = nh * te[p].c - nte * hv[p].c;            \
            const float nE    = omE * tE.c + sE * outer;                 \
            const float dnew  = omU * du[p].c + smod * nE;               \
            const float ar    = fmaxf(av[p].c, 0.f);                     \
            const float inv   = 1.0f / (ar + 1e-8f);                     \
            const float up    = fmaxf(CLIPV - wh[p].c, 0.f) * inv;       \
            const float lo    = -fmaxf(CLIPV + wh[p].c, 0.f) * inv;      \
            rE.c = nE;                                                   \
            rU.c = fmaxf(fminf(dnew, up), lo);                           \
        }
        COMP(x) COMP(y) COMP(z) COMP(w)
        #undef COMP

        __builtin_nontemporal_store(rE.x, out_tE + flat + 0);
        __builtin_nontemporal_store(rE.y, out_tE + flat + 1);
        __builtin_nontemporal_store(rE.z, out_tE + flat + 2);
        __builtin_nontemporal_store(rE.w, out_tE + flat + 3);
        __builtin_nontemporal_store(rU.x, out_dU + flat + 0);
        __builtin_nontemporal_store(rU.y, out_dU + flat + 1);
        __builtin_nontemporal_store(rU.z, out_dU + flat + 2);
        __builtin_nontemporal_store(rU.w, out_dU + flat + 3);
    }
}

extern "C" void kernel_launch(void* const* d_in, const int* in_sizes, int n_in,
                              void* d_out, int out_size, void* d_ws, size_t ws_size,
                              hipStream_t stream) {
    const float* x       = (const float*)d_in[0];
    const float* h       = (const float*)d_in[1];
    const float* v       = (const float*)d_in[2];
    const float* dU      = (const float*)d_in[3];
    const float* trace_e = (const float*)d_in[4];
    const float* trace_E = (const float*)d_in[5];
    const float* x2h_w   = (const float*)d_in[6];
    const float* x2h_b   = (const float*)d_in[7];
    const float* h2h_w   = (const float*)d_in[8];
    const float* h2h_b   = (const float*)d_in[9];
    const float* alpha   = (const float*)d_in[10];
    const float* tau_v   = (const float*)d_in[11];
    const float* tau_e   = (const float*)d_in[12];
    const float* tau_U   = (const float*)d_in[13];
    const float* tau_E   = (const float*)d_in[14];
    float* out    = (float*)d_out;
    float* mod_ws = (float*)d_ws;

    hipMemsetAsync(d_ws, 0, BB * sizeof(float), stream);

    // mod[b]: 64*32 = 2048 waves -> 512 blocks of 256
    k_mod<<<512, 256, 0, stream>>>(x, h, x2h_w, x2h_b, h2h_w, h2h_b, mod_ws);

    // fused row kernel: 64*512 = 32768 waves -> 8192 blocks of 256
    k_fused<<<8192, 256, 0, stream>>>(x, h, v, dU, trace_e, trace_E,
                                      x2h_w, x2h_b, h2h_w, h2h_b, alpha,
                                      tau_v, tau_e, tau_U, tau_E, mod_ws, out);
}

// Round 4
// 277.476 us; speedup vs baseline: 1.0381x; 1.0149x over previous
//
#include <hip/hip_runtime.h>

#define BB 64
#define DD 256
#define HH 512
#define RR 32
#define CLIPV 50.0f

// Output layout (flat fp32): v_new | new_h | dU_new | new_trace_e | new_trace_E
#define OUT_V   0
#define OUT_H   (BB * HH)                       // 32768
#define OUT_DU  (2 * BB * HH)                   // 65536
#define OUT_TE  (2 * BB * HH + BB * HH * HH)    // 16842752
#define OUT_TEE (3 * BB * HH + BB * HH * HH)    // 16875520

__device__ __forceinline__ float sigmoidf_(float x) {
    return 1.0f / (1.0f + expf(-x));
}

__device__ __forceinline__ float4 ntload4(const float* p) {
    float4 r;
    r.x = __builtin_nontemporal_load(p + 0);
    r.y = __builtin_nontemporal_load(p + 1);
    r.z = __builtin_nontemporal_load(p + 2);
    r.w = __builtin_nontemporal_load(p + 3);
    return r;
}

// mod[b] = sum_r relu(Wx[b,H+r] + Wh[b,H+r]).  One wave per (b,r): 2048 waves.
__global__ __launch_bounds__(256) void k_mod(
    const float* __restrict__ x, const float* __restrict__ h,
    const float* __restrict__ x2h_w, const float* __restrict__ x2h_b,
    const float* __restrict__ h2h_w, const float* __restrict__ h2h_b,
    float* __restrict__ mod_ws)
{
    const int wave = blockIdx.x * 4 + (threadIdx.x >> 6);
    const int lane = threadIdx.x & 63;
    const int b = wave >> 5;          // /32
    const int r = wave & (RR - 1);
    const int i = HH + r;

    float4 xv = *reinterpret_cast<const float4*>(x + b * DD + lane * 4);
    float4 wv = *reinterpret_cast<const float4*>(x2h_w + i * DD + lane * 4);
    float s = xv.x * wv.x + xv.y * wv.y + xv.z * wv.z + xv.w * wv.w;

    #pragma unroll
    for (int p = 0; p < 2; ++p) {
        const int j0 = p * 256 + lane * 4;
        float4 hv  = *reinterpret_cast<const float4*>(h + b * HH + j0);
        float4 whv = *reinterpret_cast<const float4*>(h2h_w + i * HH + j0);
        s += hv.x * whv.x + hv.y * whv.y + hv.z * whv.z + hv.w * whv.w;
    }

    #pragma unroll
    for (int off = 32; off > 0; off >>= 1)
        s += __shfl_xor(s, off, 64);

    if (lane == 0) {
        s += x2h_b[i] + h2h_b[i];
        atomicAdd(mod_ws + b, fmaxf(s, 0.f));
    }
}

// Fused: one wave per (b,i) row, i < H.  32768 waves = 8192 blocks.
// Streaming operands (dU, trace_E) use nontemporal loads; broadcast data
// (alpha, h2h_w, h, trace_e) goes through L2 normally and stays resident.
__global__ __launch_bounds__(256) void k_fused(
    const float* __restrict__ x, const float* __restrict__ h, const float* __restrict__ v,
    const float* __restrict__ dU, const float* __restrict__ trace_e,
    const float* __restrict__ trace_E,
    const float* __restrict__ x2h_w, const float* __restrict__ x2h_b,
    const float* __restrict__ h2h_w, const float* __restrict__ h2h_b,
    const float* __restrict__ alpha,
    const float* __restrict__ tau_v, const float* __restrict__ tau_e,
    const float* __restrict__ tau_U, const float* __restrict__ tau_E,
    const float* __restrict__ mod_ws, float* __restrict__ out)
{
    const int wave = blockIdx.x * 4 + (threadIdx.x >> 6);
    const int lane = threadIdx.x & 63;
    const int b = wave >> 9;          // /512
    const int i = wave & (HH - 1);
    const int bi = b * HH + i;

    // ---- reduction phase: Wx + Wh + plastic ----
    float4 xv = *reinterpret_cast<const float4*>(x + b * DD + lane * 4);
    float4 wv = *reinterpret_cast<const float4*>(x2h_w + i * DD + lane * 4);
    float s  = xv.x * wv.x + xv.y * wv.y + xv.z * wv.z + xv.w * wv.w;
    float pl = 0.0f;

    float4 hv[2], wh[2], du[2], av[2], te[2];
    #pragma unroll
    for (int p = 0; p < 2; ++p) {
        const int j0 = p * 256 + lane * 4;
        hv[p] = *reinterpret_cast<const float4*>(h + b * HH + j0);
        wh[p] = *reinterpret_cast<const float4*>(h2h_w + i * HH + j0);
        du[p] = ntload4(dU + (size_t)bi * HH + j0);
        av[p] = *reinterpret_cast<const float4*>(alpha + i * HH + j0);
        te[p] = *reinterpret_cast<const float4*>(trace_e + b * HH + j0);
        s += hv[p].x * wh[p].x + hv[p].y * wh[p].y
           + hv[p].z * wh[p].z + hv[p].w * wh[p].w;
        pl += fmaxf(av[p].x, 0.f) * du[p].x * hv[p].x
            + fmaxf(av[p].y, 0.f) * du[p].y * hv[p].y
            + fmaxf(av[p].z, 0.f) * du[p].z * hv[p].z
            + fmaxf(av[p].w, 0.f) * du[p].w * hv[p].w;
    }

    #pragma unroll
    for (int off = 32; off > 0; off >>= 1) {
        s  += __shfl_xor(s, off, 64);
        pl += __shfl_xor(pl, off, 64);
    }

    // ---- row-local scalar state (all lanes compute; same-addr loads broadcast) ----
    s += x2h_b[i] + h2h_b[i];
    const float dv = s + pl;
    const float sv = sigmoidf_(tau_v[i]);
    const float vn = (1.f - sv) * v[bi] + sv * dv;
    const float nh = fmaxf(vn, 0.f);
    const float se = sigmoidf_(tau_e[i]);
    const float nte = (1.f - se) * trace_e[bi] + se * h[bi];

    if (lane == 0) {
        out[OUT_V  + bi] = vn;
        out[OUT_H  + bi] = nh;
        out[OUT_TE + bi] = nte;
    }

    // ---- elementwise phase over the same row ----
    const float sU  = sigmoidf_(tau_U[0]);
    const float sE  = sigmoidf_(tau_E[0]);
    const float omU = 1.f - sU, omE = 1.f - sE;
    const float smod = sU * mod_ws[b];

    float* __restrict__ out_dU = out + OUT_DU;
    float* __restrict__ out_tE = out + OUT_TEE;

    #pragma unroll
    for (int p = 0; p < 2; ++p) {
        const int j0 = p * 256 + lane * 4;
        const size_t flat = (size_t)bi * HH + j0;
        float4 tE = ntload4(trace_E + flat);

        float4 rE, rU;
        #define COMP(c)                                                  \
        {                                                                \
            const float outer = nh * te[p].c - nte * hv[p].c;            \
            const float nE    = omE * tE.c + sE * outer;                 \
            const float dnew  = omU * du[p].c + smod * nE;               \
            const float ar    = fmaxf(av[p].c, 0.f);                     \
            const float inv   = 1.0f / (ar + 1e-8f);                     \
            const float up    = fmaxf(CLIPV - wh[p].c, 0.f) * inv;       \
            const float lo    = -fmaxf(CLIPV + wh[p].c, 0.f) * inv;      \
            rE.c = nE;                                                   \
            rU.c = fmaxf(fminf(dnew, up), lo);                           \
        }
        COMP(x) COMP(y) COMP(z) COMP(w)
        #undef COMP

        __builtin_nontemporal_store(rE.x, out_tE + flat + 0);
        __builtin_nontemporal_store(rE.y, out_tE + flat + 1);
        __builtin_nontemporal_store(rE.z, out_tE + flat + 2);
        __builtin_nontemporal_store(rE.w, out_tE + flat + 3);
        __builtin_nontemporal_store(rU.x, out_dU + flat + 0);
        __builtin_nontemporal_store(rU.y, out_dU + flat + 1);
        __builtin_nontemporal_store(rU.z, out_dU + flat + 2);
        __builtin_nontemporal_store(rU.w, out_dU + flat + 3);
    }
}

extern "C" void kernel_launch(void* const* d_in, const int* in_sizes, int n_in,
                              void* d_out, int out_size, void* d_ws, size_t ws_size,
                              hipStream_t stream) {
    const float* x       = (const float*)d_in[0];
    const float* h       = (const float*)d_in[1];
    const float* v       = (const float*)d_in[2];
    const float* dU      = (const float*)d_in[3];
    const float* trace_e = (const float*)d_in[4];
    const float* trace_E = (const float*)d_in[5];
    const float* x2h_w   = (const float*)d_in[6];
    const float* x2h_b   = (const float*)d_in[7];
    const float* h2h_w   = (const float*)d_in[8];
    const float* h2h_b   = (const float*)d_in[9];
    const float* alpha   = (const float*)d_in[10];
    const float* tau_v   = (const float*)d_in[11];
    const float* tau_e   = (const float*)d_in[12];
    const float* tau_U   = (const float*)d_in[13];
    const float* tau_E   = (const float*)d_in[14];
    float* out    = (float*)d_out;
    float* mod_ws = (float*)d_ws;

    hipMemsetAsync(d_ws, 0, BB * sizeof(float), stream);

    // mod[b]: 64*32 = 2048 waves -> 512 blocks of 256
    k_mod<<<512, 256, 0, stream>>>(x, h, x2h_w, x2h_b, h2h_w, h2h_b, mod_ws);

    // fused row kernel: 64*512 = 32768 waves -> 8192 blocks of 256
    k_fused<<<8192, 256, 0, stream>>>(x, h, v, dU, trace_e, trace_E,
                                      x2h_w, x2h_b, h2h_w, h2h_b, alpha,
                                      tau_v, tau_e, tau_U, tau_E, mod_ws, out);
}